// Round 9
// baseline (69.987 us; speedup 1.0000x reference)
//
#include <hip/hip_runtime.h>
#include <stdint.h>

// CachedCompressedLinear: out[b][o] = sum_k x[b][k] * ((wq[o][k]-128)*scale) + bias[o]
// x: [16][4096] f32, wq: [11008][4096] int32 codes, scale f32, bias[11008] f32.
//
// R1..R8: 4 kernel families x occupancy 10.75-21 waves/CU ALL pin at 49-61us.
// Accounting: harness fills 721MB of 0xAA between replays -> L2/L3 full of
// dirty lines -> our 181MB of cold read-allocations evict ~181MB of dirty
// writebacks. 362MB forced HBM traffic / 49.1us = 7.37 TB/s = the fill
// kernels' own ceiling -> we were at the COMBINED-traffic roofline all along.
// R9 lever: system-scope loads (sc0 sc1) on the wq stream -> no cache
// allocation -> no dirty evictions -> ~181MB pure read. Everything else
// identical to R1 (49.10us) for a clean A/B.

constexpr int IN_F  = 4096;
constexpr int OUT_F = 11008;
constexpr int NWAVES = 8;
constexpr int KPW = IN_F / NWAVES;   // 512 k per wave
constexpr int NKB = KPW / 32;        // 16 k-blocks of 32 per wave

typedef _Float16 f16x8 __attribute__((ext_vector_type(8)));
typedef float    f32x4 __attribute__((ext_vector_type(4)));

__global__ __launch_bounds__(NWAVES * 64)
void qlinear_mfma(const float* __restrict__ x,
                  const int*   __restrict__ wq,
                  const float* __restrict__ scale,
                  const float* __restrict__ bias,
                  float*       __restrict__ out)
{
    const int tid  = threadIdx.x;
    const int lane = tid & 63;
    const int wave = tid >> 6;
    const int obase = blockIdx.x * 16;

    const int ncol = lane & 15;   // B col (o_local) == A row (batch)
    const int kgrp = lane >> 4;   // 0..3

    const int o  = obase + ncol;
    const int k0 = wave * KPW + kgrp * 8;

    const float* xp = x  + (size_t)ncol * IN_F + k0;
    const int*   wp = wq + (size_t)o    * IN_F + k0;

    f32x4 acc = {0.f, 0.f, 0.f, 0.f};

    #pragma unroll 4
    for (int kb = 0; kb < NKB; ++kb) {
        const int off = kb * 32;
        const float4 xa = *reinterpret_cast<const float4*>(xp + off);
        const float4 xb = *reinterpret_cast<const float4*>(xp + off + 4);

        // system-scope loads: no L1/L2/L3 allocation -> no dirty-line
        // eviction of the harness's 721MB poison fill during our kernel
        const unsigned long long* wp64 =
            reinterpret_cast<const unsigned long long*>(wp + off);
        unsigned long long q0 = __hip_atomic_load(wp64 + 0, __ATOMIC_RELAXED, __HIP_MEMORY_SCOPE_SYSTEM);
        unsigned long long q1 = __hip_atomic_load(wp64 + 1, __ATOMIC_RELAXED, __HIP_MEMORY_SCOPE_SYSTEM);
        unsigned long long q2 = __hip_atomic_load(wp64 + 2, __ATOMIC_RELAXED, __HIP_MEMORY_SCOPE_SYSTEM);
        unsigned long long q3 = __hip_atomic_load(wp64 + 3, __ATOMIC_RELAXED, __HIP_MEMORY_SCOPE_SYSTEM);

        f16x8 af, bf;
        af[0] = (_Float16)xa.x; af[1] = (_Float16)xa.y;
        af[2] = (_Float16)xa.z; af[3] = (_Float16)xa.w;
        af[4] = (_Float16)xb.x; af[5] = (_Float16)xb.y;
        af[6] = (_Float16)xb.z; af[7] = (_Float16)xb.w;

        // codes in [0,255]; (c-128) in [-128,127] is EXACT in f16
        bf[0] = (_Float16)((int)(unsigned)(q0)        - 128);
        bf[1] = (_Float16)((int)(unsigned)(q0 >> 32)  - 128);
        bf[2] = (_Float16)((int)(unsigned)(q1)        - 128);
        bf[3] = (_Float16)((int)(unsigned)(q1 >> 32)  - 128);
        bf[4] = (_Float16)((int)(unsigned)(q2)        - 128);
        bf[5] = (_Float16)((int)(unsigned)(q2 >> 32)  - 128);
        bf[6] = (_Float16)((int)(unsigned)(q3)        - 128);
        bf[7] = (_Float16)((int)(unsigned)(q3 >> 32)  - 128);

        acc = __builtin_amdgcn_mfma_f32_16x16x32_f16(af, bf, acc, 0, 0, 0);
    }

    // ---- reduce the 8 per-wave partials (disjoint k subsets) ----
    __shared__ f32x4 red[NWAVES][64];
    red[wave][lane] = acc;
    __syncthreads();

    if (wave == 0) {
        f32x4 s = red[0][lane];
        #pragma unroll
        for (int w = 1; w < NWAVES; ++w) s += red[w][lane];

        const float sc = scale[0];
        const float bo = bias[o];
        const int   brow = kgrp * 4;   // C/D: col=lane&15 -> o, row=(lane>>4)*4+r -> batch
        #pragma unroll
        for (int r = 0; r < 4; ++r)
            out[(size_t)(brow + r) * OUT_F + o] = s[r] * sc + bo;
    }
}

extern "C" void kernel_launch(void* const* d_in, const int* in_sizes, int n_in,
                              void* d_out, int out_size, void* d_ws, size_t ws_size,
                              hipStream_t stream) {
    const float* x     = (const float*)d_in[0];
    const int*   wq    = (const int*)d_in[1];
    const float* scale = (const float*)d_in[2];
    const float* bias  = (const float*)d_in[3];
    float*       out   = (float*)d_out;

    dim3 grid(OUT_F / 16);        // 688 o-tiles
    dim3 block(NWAVES * 64);      // 512 threads
    qlinear_mfma<<<grid, block, 0, stream>>>(x, wq, scale, bias, out);
}